// Round 8
// baseline (330.078 us; speedup 1.0000x reference)
//
#include <hip/hip_runtime.h>
#include <hip/hip_bf16.h>

#define T_TOK 2048
#define HID 2048
#define IMED 768
#define NEXP 16
#define TOPK 8
#define MAXPAIR (T_TOK * TOPK)

using f32x4  = __attribute__((ext_vector_type(4))) float;
using bf16x8 = __attribute__((ext_vector_type(8))) __bf16;

__device__ __forceinline__ f32x4 mfma16(bf16x8 a, bf16x8 b, f32x4 c) {
  return __builtin_amdgcn_mfma_f32_16x16x32_bf16(a, b, c, 0, 0, 0);
}

__device__ __forceinline__ void gload16(const void* g, void* lds) {
  __builtin_amdgcn_global_load_lds((const __attribute__((address_space(1))) unsigned int*)g,
                                   (__attribute__((address_space(3))) unsigned int*)lds,
                                   16, 0, 0);
}

#define BAR() do { asm volatile("s_barrier" ::: "memory"); \
                   __builtin_amdgcn_sched_barrier(0); } while (0)
#define LGKM0() do { asm volatile("s_waitcnt lgkmcnt(0)" ::: "memory"); \
                     __builtin_amdgcn_sched_barrier(0); } while (0)
#define WAITV(N) do { asm volatile("s_waitcnt vmcnt(" #N ")" ::: "memory"); \
                      __builtin_amdgcn_sched_barrier(0); } while (0)

// ---------- prep: fp32 -> bf16 copy of hidden_states ----------
__global__ void moe_cvt_x(const float* __restrict__ X, __bf16* __restrict__ XB) {
  int i = (blockIdx.x * blockDim.x + threadIdx.x) * 8;
  float4 v0 = *(const float4*)&X[i];
  float4 v1 = *(const float4*)&X[i + 4];
  bf16x8 o;
  o[0] = (__bf16)v0.x; o[1] = (__bf16)v0.y; o[2] = (__bf16)v0.z; o[3] = (__bf16)v0.w;
  o[4] = (__bf16)v1.x; o[5] = (__bf16)v1.y; o[6] = (__bf16)v1.z; o[7] = (__bf16)v1.w;
  *(bf16x8*)&XB[i] = o;
}

// ---------- prep: per-expert transpose [R][C] f32 -> [C][R] bf16, 64x64 tiles ----------
__global__ __launch_bounds__(256) void moe_transpose(const float* __restrict__ in,
                                                     __bf16* __restrict__ out,
                                                     int R, int C) {
  __shared__ __align__(16) float tile[64][68];
  const int e = blockIdx.z;
  const float* ib = in + (size_t)e * R * C;
  __bf16* ob = out + (size_t)e * R * C;
  const int c0 = blockIdx.x * 64, r0 = blockIdx.y * 64;
  const int tid = threadIdx.x;
  const int lr = tid >> 4;
  const int lc = (tid & 15) * 4;
#pragma unroll
  for (int i = 0; i < 4; ++i) {
    int r = lr + i * 16;
    float4 v = *(const float4*)&ib[(size_t)(r0 + r) * C + c0 + lc];
    *(float4*)&tile[r][lc] = v;
  }
  __syncthreads();
  const int oc = tid >> 2;
  const int sr = (tid & 3) * 16;
  bf16x8 o0, o1;
#pragma unroll
  for (int j = 0; j < 8; ++j) o0[j] = (__bf16)tile[sr + j][oc];
#pragma unroll
  for (int j = 0; j < 8; ++j) o1[j] = (__bf16)tile[sr + 8 + j][oc];
  *(bf16x8*)&ob[(size_t)(c0 + oc) * R + r0 + sr] = o0;
  *(bf16x8*)&ob[(size_t)(c0 + oc) * R + r0 + sr + 8] = o1;
}

// ---------- routing ----------
// meta ints: [0..15]=counts  [16..32]=offsets(17)  [33..48]=cursors
__global__ void moe_route_build(const int* __restrict__ idx, const float* __restrict__ wgt,
                                float* __restrict__ combine, int* __restrict__ meta) {
  int t = blockIdx.x * blockDim.x + threadIdx.x;
  if (t >= T_TOK) return;
  float c[NEXP];
#pragma unroll
  for (int e = 0; e < NEXP; ++e) c[e] = 0.f;
  for (int k = 0; k < TOPK; ++k) c[idx[t * TOPK + k]] += wgt[t * TOPK + k];
  for (int e = 0; e < NEXP; ++e) {
    combine[t * NEXP + e] = c[e];
    if (c[e] != 0.f) atomicAdd(&meta[e], 1);
  }
}

__global__ void moe_scan(int* __restrict__ meta) {
  if (threadIdx.x == 0 && blockIdx.x == 0) {
    int s = 0;
    for (int e = 0; e < NEXP; ++e) { meta[16 + e] = s; meta[33 + e] = s; s += meta[e]; }
    meta[32] = s;
  }
}

// also builds per-token inverse map: ptok[t][0..pcnt-1] = pair index
__global__ void moe_scatter(const float* __restrict__ combine, int* __restrict__ meta,
                            int* __restrict__ route_tok, float* __restrict__ route_w,
                            int* __restrict__ ptok, int* __restrict__ pcnt) {
  int t = blockIdx.x * blockDim.x + threadIdx.x;
  if (t >= T_TOK) return;
  int slot = 0;
  for (int e = 0; e < NEXP; ++e) {
    float c = combine[t * NEXP + e];
    if (c != 0.f) {
      int p = atomicAdd(&meta[33 + e], 1);
      route_tok[p] = t;
      route_w[p] = c;
      ptok[t * TOPK + slot] = p;
      ++slot;
    }
  }
  pcnt[t] = slot;
}

// ---------- GEMM1: m201-style 8-wave deep pipeline ----------
// BM=256 pairs x BN=256 B-rows (128 gate + 128 up of a 128-I window), K=2048.
// K-step=32: slot = A 16KB + B 16KB; 4-slot ring (128KB LDS), stage-3-ahead,
// counted vmcnt(8) at step boundary. 2 phases/step, 16 MFMA per phase,
// wave tile 128x64 (2M x 4N waves).
__global__ __launch_bounds__(512, 2) void moe_gemm1(
    const __bf16* __restrict__ XB, const __bf16* __restrict__ WguT,
    const int* __restrict__ rtok, const float* __restrict__ rw,
    const int* __restrict__ meta, __bf16* __restrict__ ACT) {
  const int orig = blockIdx.x;               // 768 = 8 XCDs x 96
  const int wgid = (orig & 7) * 96 + (orig >> 3);
  const int e   = wgid / 48;
  const int rem = wgid % 48;
  const int ny  = rem >> 3;                  // 0..5
  const int mx  = rem & 7;                   // 0..7

  const int seg0 = meta[16 + e];
  const int cnt  = meta[16 + e + 1] - seg0;
  const int m0 = mx * 256;
  if (m0 >= cnt) return;
  const int n0 = ny * 128;

  __shared__ __align__(16) char As[4 * 16384];
  __shared__ __align__(16) char Bs[4 * 16384];

  const int tid = threadIdx.x;
  const int l = tid & 63;
  const int w = tid >> 6;                    // 0..7
  const int wm = w >> 2, wn = w & 3;         // wave tile 128x64

  // staging sources: 2 rounds each; LDS rows are 64B (K=32), slot-XOR swizzled.
  const char* baseA[2];
  const char* baseB[2];
#pragma unroll
  for (int q = 0; q < 2; ++q) {
    const int row = (w * 2 + q) * 16 + (l >> 2);       // 0..255
    const int g   = (l & 3) ^ ((row >> 1) & 3);        // inverse-swizzled k-group
    int grow = m0 + row; if (grow >= cnt) grow = cnt - 1;
    const int tok = rtok[seg0 + grow];
    baseA[q] = (const char*)(XB + (size_t)tok * HID) + g * 16;
    const int sec = row >> 6, s = row & 63;
    const int wr = (s < 32) ? (n0 + sec * 32 + s) : (IMED + n0 + sec * 32 + (s - 32));
    baseB[q] = (const char*)(WguT + ((size_t)e * (2 * IMED) + wr) * HID) + g * 16;
  }

  f32x4 acc[8][4];   // ni 0,1 = gate ; 2,3 = up (same 32-col window per wave)
  const f32x4 zero = {0.f, 0.f, 0.f, 0.f};
#pragma unroll
  for (int i = 0; i < 8; ++i)
#pragma unroll
    for (int j = 0; j < 4; ++j) acc[i][j] = zero;

  auto STAGE_A = [&](int slot, int t) {
#pragma unroll
    for (int q = 0; q < 2; ++q)
      gload16(baseA[q] + t * 64, &As[slot * 16384 + (w * 2 + q) * 1024]);
  };
  auto STAGE_B = [&](int slot, int t) {
#pragma unroll
    for (int q = 0; q < 2; ++q)
      gload16(baseB[q] + t * 64, &Bs[slot * 16384 + (w * 2 + q) * 1024]);
  };

  // fragment read offset: row (l&15) within 16-row frag, k-group (l>>4),
  // swizzle slot = (l>>4) ^ ((l>>1)&3)  (2-way bank alias = free)
  const int rdbase = (l & 15) * 64 + (((l >> 4) ^ ((l >> 1) & 3)) * 16);

  const int NT = HID / 32;                   // 64 K-steps
  STAGE_A(0, 0); STAGE_B(0, 0);
  STAGE_A(1, 1); STAGE_B(1, 1);
  STAGE_A(2, 2); STAGE_B(2, 2);
  WAITV(8); BAR();                            // slot0 landed

#pragma unroll 1
  for (int t = 0; t < NT; ++t) {
    const char* Ab = &As[(t & 3) * 16384] + wm * 8192 + rdbase;
    const char* Bb = &Bs[(t & 3) * 16384] + wn * 4096 + rdbase;
    bf16x8 af[4], bf[4];
    // ---- phase 0: m0-3 quadrant ----
#pragma unroll
    for (int mi = 0; mi < 4; ++mi) af[mi] = *(const bf16x8*)(Ab + mi * 1024);
#pragma unroll
    for (int ni = 0; ni < 4; ++ni) bf[ni] = *(const bf16x8*)(Bb + ni * 1024);
    if (t + 3 < NT) STAGE_A((t + 3) & 3, t + 3);
    BAR(); LGKM0();
    __builtin_amdgcn_s_setprio(1);
#pragma unroll
    for (int mi = 0; mi < 4; ++mi)
#pragma unroll
      for (int ni = 0; ni < 4; ++ni)
        acc[mi][ni] = mfma16(af[mi], bf[ni], acc[mi][ni]);
    __builtin_amdgcn_s_setprio(0);
    BAR();
    // ---- phase 1: m4-7 quadrant (bf reused) ----
#pragma unroll
    for (int mi = 0; mi < 4; ++mi) af[mi] = *(const bf16x8*)(Ab + (4 + mi) * 1024);
    if (t + 3 < NT) STAGE_B((t + 3) & 3, t + 3);
    BAR(); LGKM0();
    __builtin_amdgcn_s_setprio(1);
#pragma unroll
    for (int mi = 0; mi < 4; ++mi)
#pragma unroll
      for (int ni = 0; ni < 4; ++ni)
        acc[4 + mi][ni] = mfma16(af[mi], bf[ni], acc[4 + mi][ni]);
    __builtin_amdgcn_s_setprio(0);
    // counted boundary wait: next slot (t+1) landed across all waves
    if (t + 3 < NT)      { WAITV(8); }
    else if (t + 2 < NT) { WAITV(4); }
    else if (t + 1 < NT) { WAITV(0); }
    BAR();
  }

  const int cbase = n0 + wn * 32;
#pragma unroll
  for (int mi = 0; mi < 8; ++mi) {
    const int rb = wm * 128 + mi * 16 + ((l >> 4) << 2);
#pragma unroll
    for (int r = 0; r < 4; ++r) {
      const int row = m0 + rb + r;
      if (row < cnt) {
        const float wgt = rw[seg0 + row];
#pragma unroll
        for (int ni = 0; ni < 2; ++ni) {
          const float g = acc[mi][ni][r];
          const float u = acc[mi][ni + 2][r];
          const float s = g / (1.f + __expf(-g));
          ACT[(size_t)(seg0 + row) * IMED + cbase + ni * 16 + (l & 15)] = (__bf16)(s * u * wgt);
        }
      }
    }
  }
}

// ---------- GEMM2: 128 pairs x 128 H-cols, K=768, single-buffer, bf16 store ----------
__global__ __launch_bounds__(256) void moe_gemm2(
    const __bf16* __restrict__ ACT, const __bf16* __restrict__ WdT,
    const int* __restrict__ meta, __bf16* __restrict__ ACT2) {
  const int orig = blockIdx.x;               // 4096 WGs = 8 x 512
  const int wgid = (orig & 7) * 512 + (orig >> 3);
  const int mx = wgid & 15;
  const int ny = (wgid >> 4) & 15;
  const int e  = wgid >> 8;

  const int seg0 = meta[16 + e];
  const int cnt  = meta[16 + e + 1] - seg0;
  const int m0 = mx * 128;
  if (m0 >= cnt) return;
  const int n0 = ny * 128;

  __shared__ char As[16384];
  __shared__ char Bs[16384];

  const int tid = threadIdx.x;
  const int l = tid & 63;
  const int w = tid >> 6;
  const int wm = w >> 1, wn = w & 1;
  const int swoff = 16 * ((l & 7) ^ (l >> 3));

  const char* baseA[4];
  const char* baseB[4];
#pragma unroll
  for (int q = 0; q < 4; ++q) {
    const int r = (w * 4 + q) * 8 + (l >> 3);
    int grow = m0 + r; if (grow >= cnt) grow = cnt - 1;
    baseA[q] = (const char*)(ACT + (size_t)(seg0 + grow) * IMED) + swoff;
    baseB[q] = (const char*)(WdT + ((size_t)e * HID + n0 + r) * IMED) + swoff;
  }

  f32x4 acc[4][4];
  const f32x4 zero = {0.f, 0.f, 0.f, 0.f};
#pragma unroll
  for (int i = 0; i < 4; ++i)
#pragma unroll
    for (int j = 0; j < 4; ++j) acc[i][j] = zero;

  for (int k0b = 0; k0b < IMED * 2; k0b += 128) {
#pragma unroll
    for (int q = 0; q < 4; ++q) {
      gload16(baseA[q] + k0b, &As[(w * 4 + q) * 1024]);
      gload16(baseB[q] + k0b, &Bs[(w * 4 + q) * 1024]);
    }
    __syncthreads();
#pragma unroll
    for (int ks = 0; ks < 2; ++ks) {
      const int colb = ks * 64 + (l >> 4) * 16;
      bf16x8 af[4], bf[4];
#pragma unroll
      for (int mi = 0; mi < 4; ++mi) {
        const int row = wm * 64 + mi * 16 + (l & 15);
        af[mi] = *(const bf16x8*)&As[row * 128 + (colb ^ ((row & 7) << 4))];
      }
#pragma unroll
      for (int ni = 0; ni < 4; ++ni) {
        const int row = wn * 64 + ni * 16 + (l & 15);
        bf[ni] = *(const bf16x8*)&Bs[row * 128 + (colb ^ ((row & 7) << 4))];
      }
#pragma unroll
      for (int mi = 0; mi < 4; ++mi)
#pragma unroll
        for (int ni = 0; ni < 4; ++ni)
          acc[mi][ni] = mfma16(af[mi], bf[ni], acc[mi][ni]);
    }
    __syncthreads();
  }

#pragma unroll
  for (int mi = 0; mi < 4; ++mi) {
    const int rb = wm * 64 + mi * 16 + ((l >> 4) << 2);
#pragma unroll
    for (int r = 0; r < 4; ++r) {
      const int row = m0 + rb + r;
      if (row < cnt) {
#pragma unroll
        for (int ni = 0; ni < 4; ++ni)
          ACT2[(size_t)(seg0 + row) * HID + n0 + wn * 64 + ni * 16 + (l & 15)] =
              (__bf16)acc[mi][ni][r];
      }
    }
  }
}

// ---------- combine: out[t][h] = sum_k ACT2[ptok[t][k]][h] ----------
__global__ __launch_bounds__(256) void moe_combine(const __bf16* __restrict__ ACT2,
                                                   const int* __restrict__ ptok,
                                                   const int* __restrict__ pcnt,
                                                   float* __restrict__ out) {
  const int t = blockIdx.x;
  const int h = threadIdx.x * 8;
  const int n = pcnt[t];
  float a[8];
#pragma unroll
  for (int j = 0; j < 8; ++j) a[j] = 0.f;
  for (int k = 0; k < n; ++k) {
    const int p = ptok[t * TOPK + k];
    bf16x8 v = *(const bf16x8*)&ACT2[(size_t)p * HID + h];
#pragma unroll
    for (int j = 0; j < 8; ++j) a[j] += (float)v[j];
  }
  float4 o0 = {a[0], a[1], a[2], a[3]};
  float4 o1 = {a[4], a[5], a[6], a[7]};
  *(float4*)&out[(size_t)t * HID + h] = o0;
  *(float4*)&out[(size_t)t * HID + h + 4] = o1;
}

extern "C" void kernel_launch(void* const* d_in, const int* in_sizes, int n_in,
                              void* d_out, int out_size, void* d_ws, size_t ws_size,
                              hipStream_t stream) {
  const float* X   = (const float*)d_in[0];
  const float* GUP = (const float*)d_in[1];
  const float* DP  = (const float*)d_in[2];
  const int*   IDX = (const int*)d_in[3];
  const float* W   = (const float*)d_in[4];
  float* out = (float*)d_out;

  size_t off = 0;
  auto alloc = [&](size_t bytes) -> void* {
    void* p = (char*)d_ws + off;
    off = (off + bytes + 255) & ~(size_t)255;
    return p;
  };
  __bf16* XB      = (__bf16*)alloc((size_t)T_TOK * HID * 2);
  __bf16* WguT    = (__bf16*)alloc((size_t)NEXP * 2 * IMED * HID * 2);
  __bf16* WdT     = (__bf16*)alloc((size_t)NEXP * HID * IMED * 2);
  __bf16* ACT     = (__bf16*)alloc((size_t)(MAXPAIR + 256) * IMED * 2);
  float*  combine = (float*)alloc((size_t)T_TOK * NEXP * 4);
  int*    meta    = (int*)alloc(64 * 4);
  int*    rtok    = (int*)alloc((size_t)MAXPAIR * 4);
  float*  rw      = (float*)alloc((size_t)MAXPAIR * 4);
  int*    ptok    = (int*)alloc((size_t)T_TOK * TOPK * 4);
  int*    pcnt    = (int*)alloc((size_t)T_TOK * 4);
  if (off > ws_size) return;

  // ACT2 aliases WguT: GEMM1 (last reader of WguT) completes before GEMM2
  // (first writer of ACT2) on the same stream.
  __bf16* ACT2 = WguT;

  hipMemsetAsync(meta, 0, 256, stream);
  moe_cvt_x<<<T_TOK * HID / (256 * 8), 256, 0, stream>>>(X, XB);
  moe_transpose<<<dim3((2 * IMED) / 64, HID / 64, NEXP), 256, 0, stream>>>(GUP, WguT, HID, 2 * IMED);
  moe_transpose<<<dim3(HID / 64, IMED / 64, NEXP), 256, 0, stream>>>(DP, WdT, IMED, HID);
  moe_route_build<<<T_TOK / 256, 256, 0, stream>>>(IDX, W, combine, meta);
  moe_scan<<<1, 64, 0, stream>>>(meta);
  moe_scatter<<<T_TOK / 256, 256, 0, stream>>>(combine, meta, rtok, rw, ptok, pcnt);
  moe_gemm1<<<768, 512, 0, stream>>>(XB, WguT, rtok, rw, meta, ACT);
  moe_gemm2<<<4096, 256, 0, stream>>>(ACT, WdT, meta, ACT2);
  moe_combine<<<T_TOK, 256, 0, stream>>>(ACT2, ptok, pcnt, out);
}

// Round 9
// 329.597 us; speedup vs baseline: 1.0015x; 1.0015x over previous
//
#include <hip/hip_runtime.h>
#include <hip/hip_bf16.h>

#define T_TOK 2048
#define HID 2048
#define IMED 768
#define NEXP 16
#define TOPK 8
#define MAXPAIR (T_TOK * TOPK)

using f32x4  = __attribute__((ext_vector_type(4))) float;
using bf16x8 = __attribute__((ext_vector_type(8))) __bf16;

__device__ __forceinline__ f32x4 mfma16(bf16x8 a, bf16x8 b, f32x4 c) {
  return __builtin_amdgcn_mfma_f32_16x16x32_bf16(a, b, c, 0, 0, 0);
}

__device__ __forceinline__ void gload16(const void* g, void* lds) {
  __builtin_amdgcn_global_load_lds((const __attribute__((address_space(1))) unsigned int*)g,
                                   (__attribute__((address_space(3))) unsigned int*)lds,
                                   16, 0, 0);
}

// ---------- prep: fp32 -> bf16 copy of hidden_states ----------
__global__ void moe_cvt_x(const float* __restrict__ X, __bf16* __restrict__ XB) {
  int i = (blockIdx.x * blockDim.x + threadIdx.x) * 8;
  float4 v0 = *(const float4*)&X[i];
  float4 v1 = *(const float4*)&X[i + 4];
  bf16x8 o;
  o[0] = (__bf16)v0.x; o[1] = (__bf16)v0.y; o[2] = (__bf16)v0.z; o[3] = (__bf16)v0.w;
  o[4] = (__bf16)v1.x; o[5] = (__bf16)v1.y; o[6] = (__bf16)v1.z; o[7] = (__bf16)v1.w;
  *(bf16x8*)&XB[i] = o;
}

// ---------- prep: per-expert transpose [R][C] f32 -> [C][R] bf16, 64x64 tiles ----------
__global__ __launch_bounds__(256) void moe_transpose(const float* __restrict__ in,
                                                     __bf16* __restrict__ out,
                                                     int R, int C) {
  __shared__ __align__(16) float tile[64][68];
  const int e = blockIdx.z;
  const float* ib = in + (size_t)e * R * C;
  __bf16* ob = out + (size_t)e * R * C;
  const int c0 = blockIdx.x * 64, r0 = blockIdx.y * 64;
  const int tid = threadIdx.x;
  const int lr = tid >> 4;
  const int lc = (tid & 15) * 4;
#pragma unroll
  for (int i = 0; i < 4; ++i) {
    int r = lr + i * 16;
    float4 v = *(const float4*)&ib[(size_t)(r0 + r) * C + c0 + lc];
    *(float4*)&tile[r][lc] = v;
  }
  __syncthreads();
  const int oc = tid >> 2;
  const int sr = (tid & 3) * 16;
  bf16x8 o0, o1;
#pragma unroll
  for (int j = 0; j < 8; ++j) o0[j] = (__bf16)tile[sr + j][oc];
#pragma unroll
  for (int j = 0; j < 8; ++j) o1[j] = (__bf16)tile[sr + 8 + j][oc];
  *(bf16x8*)&ob[(size_t)(c0 + oc) * R + r0 + sr] = o0;
  *(bf16x8*)&ob[(size_t)(c0 + oc) * R + r0 + sr + 8] = o1;
}

// ---------- fused routing: counts + offsets + block-prefix + scatter ----------
// meta ints: [0..15]=counts  [16..32]=pair offsets(17)  [49..65]=128-blk prefix(17)
__global__ __launch_bounds__(1024) void moe_route(const int* __restrict__ idx,
                                                  const float* __restrict__ wgt,
                                                  int* __restrict__ meta,
                                                  int* __restrict__ rtok,
                                                  float* __restrict__ rw,
                                                  int* __restrict__ ptok,
                                                  int* __restrict__ pcnt) {
  __shared__ int cntS[NEXP];
  __shared__ int curS[NEXP];
  const int tid = threadIdx.x;
  if (tid < NEXP) cntS[tid] = 0;
  __syncthreads();

  const int t0 = tid, t1 = tid + 1024;
  float c0[NEXP], c1[NEXP];
#pragma unroll
  for (int e = 0; e < NEXP; ++e) { c0[e] = 0.f; c1[e] = 0.f; }
  for (int k = 0; k < TOPK; ++k) {
    c0[idx[t0 * TOPK + k]] += wgt[t0 * TOPK + k];
    c1[idx[t1 * TOPK + k]] += wgt[t1 * TOPK + k];
  }
  int n0 = 0, n1 = 0;
#pragma unroll
  for (int e = 0; e < NEXP; ++e) {
    if (c0[e] != 0.f) { atomicAdd(&cntS[e], 1); ++n0; }
    if (c1[e] != 0.f) { atomicAdd(&cntS[e], 1); ++n1; }
  }
  pcnt[t0] = n0; pcnt[t1] = n1;
  __syncthreads();

  if (tid == 0) {
    int s = 0, b = 0;
    for (int e = 0; e < NEXP; ++e) {
      meta[e] = cntS[e];
      meta[16 + e] = s;
      meta[49 + e] = b;
      curS[e] = s;
      s += cntS[e];
      b += (cntS[e] + 127) >> 7;
    }
    meta[32] = s;
    meta[65] = b;
  }
  __syncthreads();

  int s0 = 0, s1 = 0;
#pragma unroll
  for (int e = 0; e < NEXP; ++e) {
    if (c0[e] != 0.f) {
      int p = atomicAdd(&curS[e], 1);
      rtok[p] = t0; rw[p] = c0[e];
      ptok[t0 * TOPK + s0] = p; ++s0;
    }
    if (c1[e] != 0.f) {
      int p = atomicAdd(&curS[e], 1);
      rtok[p] = t1; rw[p] = c1[e];
      ptok[t1 * TOPK + s1] = p; ++s1;
    }
  }
}

// ---------- GEMM1: 128 pairs x (64 gate + 64 up cols), K=2048 ----------
// m97 structure: single 32KB LDS buffer. Flat work-queue over live m-blocks.
__global__ __launch_bounds__(256) void moe_gemm1(
    const __bf16* __restrict__ XB, const __bf16* __restrict__ WguT,
    const int* __restrict__ rtok, const float* __restrict__ rw,
    const int* __restrict__ meta, __bf16* __restrict__ ACT) {
  // 1728 WGs = 8 XCDs x 216 (bijective); wgid = ny*144 + bi.
  const int orig = blockIdx.x;
  const int wgid = (orig & 7) * 216 + (orig >> 3);
  const int ny = wgid / 144;                 // 0..11
  const int bi = wgid % 144;
  if (bi >= meta[65]) return;
  int e = 0;
#pragma unroll
  for (int k = 1; k < NEXP; ++k) if (meta[49 + k] <= bi) e = k;
  const int mx = bi - meta[49 + e];

  const int seg0 = meta[16 + e];
  const int cnt  = meta[16 + e + 1] - seg0;
  const int m0 = mx * 128;                   // < cnt by construction
  const int n0 = ny * 64;

  __shared__ char As[16384];   // 128 rows x 128B, linear; src pre-swizzled
  __shared__ char Bs[16384];

  const int tid = threadIdx.x;
  const int l = tid & 63;
  const int w = tid >> 6;
  const int wm = w >> 1, wn = w & 1;
  const int swoff = 16 * ((l & 7) ^ (l >> 3));

  const char* baseA[4];
  const char* baseB[4];
#pragma unroll
  for (int q = 0; q < 4; ++q) {
    const int r = (w * 4 + q) * 8 + (l >> 3);
    int grow = m0 + r; if (grow >= cnt) grow = cnt - 1;
    const int tok = rtok[seg0 + grow];
    baseA[q] = (const char*)(XB + (size_t)tok * HID) + swoff;
    const int sec = r >> 6, s = r & 63;
    const int wrow = (s < 32) ? (n0 + sec * 32 + s) : (IMED + n0 + sec * 32 + (s - 32));
    baseB[q] = (const char*)(WguT + ((size_t)e * (2 * IMED) + wrow) * HID) + swoff;
  }

  f32x4 acc[4][4];   // ni 0,1 = gate ; 2,3 = up
  const f32x4 zero = {0.f, 0.f, 0.f, 0.f};
#pragma unroll
  for (int i = 0; i < 4; ++i)
#pragma unroll
    for (int j = 0; j < 4; ++j) acc[i][j] = zero;

  for (int k0b = 0; k0b < HID * 2; k0b += 128) {
#pragma unroll
    for (int q = 0; q < 4; ++q) {
      gload16(baseA[q] + k0b, &As[(w * 4 + q) * 1024]);
      gload16(baseB[q] + k0b, &Bs[(w * 4 + q) * 1024]);
    }
    __syncthreads();
#pragma unroll
    for (int ks = 0; ks < 2; ++ks) {
      const int colb = ks * 64 + (l >> 4) * 16;
      bf16x8 af[4], bf[4];
#pragma unroll
      for (int mi = 0; mi < 4; ++mi) {
        const int row = wm * 64 + mi * 16 + (l & 15);
        af[mi] = *(const bf16x8*)&As[row * 128 + (colb ^ ((row & 7) << 4))];
      }
#pragma unroll
      for (int ni = 0; ni < 4; ++ni) {
        const int row = wn * 64 + ni * 16 + (l & 15);
        bf[ni] = *(const bf16x8*)&Bs[row * 128 + (colb ^ ((row & 7) << 4))];
      }
#pragma unroll
      for (int mi = 0; mi < 4; ++mi)
#pragma unroll
        for (int ni = 0; ni < 4; ++ni)
          acc[mi][ni] = mfma16(af[mi], bf[ni], acc[mi][ni]);
    }
    __syncthreads();
  }

  const int cbase = n0 + wn * 32;
#pragma unroll
  for (int mi = 0; mi < 4; ++mi) {
    const int rb = wm * 64 + mi * 16 + ((l >> 4) << 2);
#pragma unroll
    for (int r = 0; r < 4; ++r) {
      const int row = m0 + rb + r;
      if (row < cnt) {
        const float wgt = rw[seg0 + row];
#pragma unroll
        for (int ni = 0; ni < 2; ++ni) {
          const float g = acc[mi][ni][r];
          const float u = acc[mi][ni + 2][r];
          const float s = g / (1.f + __expf(-g));
          ACT[(size_t)(seg0 + row) * IMED + cbase + ni * 16 + (l & 15)] = (__bf16)(s * u * wgt);
        }
      }
    }
  }
}

// ---------- GEMM2: 128 pairs x 128 H-cols, K=768, single-buffer, bf16 store ----------
__global__ __launch_bounds__(256) void moe_gemm2(
    const __bf16* __restrict__ ACT, const __bf16* __restrict__ WdT,
    const int* __restrict__ meta, __bf16* __restrict__ ACT2) {
  // 2304 WGs = 8 XCDs x 288 (bijective); wgid = ny*144 + bi.
  const int orig = blockIdx.x;
  const int wgid = (orig & 7) * 288 + (orig >> 3);
  const int ny = wgid / 144;                 // 0..15
  const int bi = wgid % 144;
  if (bi >= meta[65]) return;
  int e = 0;
#pragma unroll
  for (int k = 1; k < NEXP; ++k) if (meta[49 + k] <= bi) e = k;
  const int mx = bi - meta[49 + e];

  const int seg0 = meta[16 + e];
  const int cnt  = meta[16 + e + 1] - seg0;
  const int m0 = mx * 128;
  const int n0 = ny * 128;

  __shared__ char As[16384];
  __shared__ char Bs[16384];

  const int tid = threadIdx.x;
  const int l = tid & 63;
  const int w = tid >> 6;
  const int wm = w >> 1, wn = w & 1;
  const int swoff = 16 * ((l & 7) ^ (l >> 3));

  const char* baseA[4];
  const char* baseB[4];
#pragma unroll
  for (int q = 0; q < 4; ++q) {
    const int r = (w * 4 + q) * 8 + (l >> 3);
    int grow = m0 + r; if (grow >= cnt) grow = cnt - 1;
    baseA[q] = (const char*)(ACT + (size_t)(seg0 + grow) * IMED) + swoff;
    baseB[q] = (const char*)(WdT + ((size_t)e * HID + n0 + r) * IMED) + swoff;
  }

  f32x4 acc[4][4];
  const f32x4 zero = {0.f, 0.f, 0.f, 0.f};
#pragma unroll
  for (int i = 0; i < 4; ++i)
#pragma unroll
    for (int j = 0; j < 4; ++j) acc[i][j] = zero;

  for (int k0b = 0; k0b < IMED * 2; k0b += 128) {
#pragma unroll
    for (int q = 0; q < 4; ++q) {
      gload16(baseA[q] + k0b, &As[(w * 4 + q) * 1024]);
      gload16(baseB[q] + k0b, &Bs[(w * 4 + q) * 1024]);
    }
    __syncthreads();
#pragma unroll
    for (int ks = 0; ks < 2; ++ks) {
      const int colb = ks * 64 + (l >> 4) * 16;
      bf16x8 af[4], bf[4];
#pragma unroll
      for (int mi = 0; mi < 4; ++mi) {
        const int row = wm * 64 + mi * 16 + (l & 15);
        af[mi] = *(const bf16x8*)&As[row * 128 + (colb ^ ((row & 7) << 4))];
      }
#pragma unroll
      for (int ni = 0; ni < 4; ++ni) {
        const int row = wn * 64 + ni * 16 + (l & 15);
        bf[ni] = *(const bf16x8*)&Bs[row * 128 + (colb ^ ((row & 7) << 4))];
      }
#pragma unroll
      for (int mi = 0; mi < 4; ++mi)
#pragma unroll
        for (int ni = 0; ni < 4; ++ni)
          acc[mi][ni] = mfma16(af[mi], bf[ni], acc[mi][ni]);
    }
    __syncthreads();
  }

#pragma unroll
  for (int mi = 0; mi < 4; ++mi) {
    const int rb = wm * 64 + mi * 16 + ((l >> 4) << 2);
#pragma unroll
    for (int r = 0; r < 4; ++r) {
      const int row = m0 + rb + r;
      if (row < cnt) {
#pragma unroll
        for (int ni = 0; ni < 4; ++ni)
          ACT2[(size_t)(seg0 + row) * HID + n0 + wn * 64 + ni * 16 + (l & 15)] =
              (__bf16)acc[mi][ni][r];
      }
    }
  }
}

// ---------- combine: out[t][h] = sum_k ACT2[ptok[t][k]][h] ----------
__global__ __launch_bounds__(256) void moe_combine(const __bf16* __restrict__ ACT2,
                                                   const int* __restrict__ ptok,
                                                   const int* __restrict__ pcnt,
                                                   float* __restrict__ out) {
  const int t = blockIdx.x;
  const int h = threadIdx.x * 8;
  const int n = pcnt[t];
  float a[8];
#pragma unroll
  for (int j = 0; j < 8; ++j) a[j] = 0.f;
  for (int k = 0; k < n; ++k) {
    const int p = ptok[t * TOPK + k];
    bf16x8 v = *(const bf16x8*)&ACT2[(size_t)p * HID + h];
#pragma unroll
    for (int j = 0; j < 8; ++j) a[j] += (float)v[j];
  }
  float4 o0 = {a[0], a[1], a[2], a[3]};
  float4 o1 = {a[4], a[5], a[6], a[7]};
  *(float4*)&out[(size_t)t * HID + h] = o0;
  *(float4*)&out[(size_t)t * HID + h + 4] = o1;
}

extern "C" void kernel_launch(void* const* d_in, const int* in_sizes, int n_in,
                              void* d_out, int out_size, void* d_ws, size_t ws_size,
                              hipStream_t stream) {
  const float* X   = (const float*)d_in[0];
  const float* GUP = (const float*)d_in[1];
  const float* DP  = (const float*)d_in[2];
  const int*   IDX = (const int*)d_in[3];
  const float* W   = (const float*)d_in[4];
  float* out = (float*)d_out;

  size_t off = 0;
  auto alloc = [&](size_t bytes) -> void* {
    void* p = (char*)d_ws + off;
    off = (off + bytes + 255) & ~(size_t)255;
    return p;
  };
  __bf16* XB      = (__bf16*)alloc((size_t)T_TOK * HID * 2);
  __bf16* WguT    = (__bf16*)alloc((size_t)NEXP * 2 * IMED * HID * 2);
  __bf16* WdT     = (__bf16*)alloc((size_t)NEXP * HID * IMED * 2);
  __bf16* ACT     = (__bf16*)alloc((size_t)(MAXPAIR + 128) * IMED * 2);
  int*    meta    = (int*)alloc(128 * 4);
  int*    rtok    = (int*)alloc((size_t)MAXPAIR * 4);
  float*  rw      = (float*)alloc((size_t)MAXPAIR * 4);
  int*    ptok    = (int*)alloc((size_t)T_TOK * TOPK * 4);
  int*    pcnt    = (int*)alloc((size_t)T_TOK * 4);
  if (off > ws_size) return;

  // ACT2 aliases WguT: GEMM1 (last reader of WguT) completes before GEMM2
  // (first writer of ACT2) on the same stream.
  __bf16* ACT2 = WguT;

  moe_cvt_x<<<T_TOK * HID / (256 * 8), 256, 0, stream>>>(X, XB);
  moe_transpose<<<dim3((2 * IMED) / 64, HID / 64, NEXP), 256, 0, stream>>>(GUP, WguT, HID, 2 * IMED);
  moe_transpose<<<dim3(HID / 64, IMED / 64, NEXP), 256, 0, stream>>>(DP, WdT, IMED, HID);
  moe_route<<<1, 1024, 0, stream>>>(IDX, W, meta, rtok, rw, ptok, pcnt);
  moe_gemm1<<<1728, 256, 0, stream>>>(XB, WguT, rtok, rw, meta, ACT);
  moe_gemm2<<<2304, 256, 0, stream>>>(ACT, WdT, meta, ACT2);
  moe_combine<<<T_TOK, 256, 0, stream>>>(ACT2, ptok, pcnt, out);
}